// Round 17
// baseline (287.685 us; speedup 1.0000x reference)
//
#include <hip/hip_runtime.h>
#include <hip/hip_fp16.h>
#include <math.h>

#define D_NODE 12
#define HS     16     // padded row stride for hidden buffers (elements)
#define BSH    7      // bucket shift: 128 nodes per bucket
#define BSZ    128
#define CHUNK  8192   // edges per partition block (P1/P2)
#define HALF   4096   // staging half-chunk (P2)
#define MAXNB  1024   // max buckets supported (nn <= 131072)

__device__ __forceinline__ int wave_iscan(int v, int lane) {
#pragma unroll
    for (int d = 1; d < 64; d <<= 1) {
        int u = __shfl_up(v, d, 64);
        if (lane >= d) v += u;
    }
    return v;
}

__device__ __forceinline__ uint2 pack4(float4 a) {
    __half2 lo = __floats2half2_rn(a.x, a.y);
    __half2 hi = __floats2half2_rn(a.z, a.w);
    uint2 r;
    r.x = *reinterpret_cast<unsigned*>(&lo);
    r.y = *reinterpret_cast<unsigned*>(&hi);
    return r;
}

__device__ __forceinline__ float4 unpack4(unsigned ux, unsigned uy) {
    __half2 lo = *reinterpret_cast<__half2*>(&ux);
    __half2 hi = *reinterpret_cast<__half2*>(&uy);
    float2 f0 = __half22float2(lo), f1 = __half22float2(hi);
    return make_float4(f0.x, f0.y, f1.x, f1.y);
}

__device__ __forceinline__ float gat16(const __half* __restrict__ tab, unsigned s, int l) {
    return __half2float(tab[((long long)s << 4) + l]);
}

__device__ __forceinline__ float msgf(float hs, uint2 at,
                                      float w0, float w1, float w2, float w3, float b) {
    float4 a = unpack4(at.x, at.y);
    return fmaxf(hs + b + w0 * a.x + w1 * a.y + w2 * a.z + w3 * a.w, 0.f);
}

// ---------------- convert x to padded fp16 table [nn][16]
__global__ __launch_bounds__(256) void k_xcvt(
    const float* __restrict__ x, long long nn, __half* __restrict__ xp)
{
    long long idx = (long long)blockIdx.x * 256 + threadIdx.x;
    if (idx >= nn * HS) return;
    long long n = idx >> 4;
    int l = (int)(idx & 15);
    xp[idx] = __float2half_rn((l < D_NODE) ? x[n * D_NODE + l] : 0.f);
}

// ---------------- P1: per-(block,bucket) histogram of dst
__global__ __launch_bounds__(1024) void k_p1(
    const int* __restrict__ ei, long long ne, int NB, int* __restrict__ M)
{
    __shared__ int cnt[MAXNB];
    int t = threadIdx.x;
    for (int k = t; k < NB; k += 1024) cnt[k] = 0;
    __syncthreads();
    long long beg = (long long)blockIdx.x * CHUNK;
    long long end = beg + CHUNK; if (end > ne) end = ne;
    for (long long e = beg + t; e < end; e += 1024)
        atomicAdd(&cnt[ei[ne + e] >> BSH], 1);
    __syncthreads();
    int* row = M + (long long)blockIdx.x * NB;
    for (int k = t; k < NB; k += 1024) row[k] = cnt[k];
}

// ---------------- per-bucket column scan over blocks (wave-shuffle scan)
__global__ __launch_bounds__(256) void k_colscan(
    int* __restrict__ M, int nblk, int NB, int* __restrict__ tot)
{
    __shared__ int wsum[4];
    int k = blockIdx.x;
    int t = threadIdx.x;
    int lane = t & 63, wv = t >> 6;
    int v[4]; int s = 0;                       // supports nblk <= 1024
#pragma unroll
    for (int j = 0; j < 4; ++j) {
        int b = t * 4 + j;
        v[j] = (b < nblk) ? M[(long long)b * NB + k] : 0;
        s += v[j];
    }
    int inc = wave_iscan(s, lane);
    if (lane == 63) wsum[wv] = inc;
    __syncthreads();
    int base = inc - s;
#pragma unroll
    for (int j = 0; j < 4; ++j) { if (j < wv) base += wsum[j]; }
#pragma unroll
    for (int j = 0; j < 4; ++j) {
        int b = t * 4 + j;
        if (b < nblk) { M[(long long)b * NB + k] = base; base += v[j]; }
    }
    if (t == 255) tot[k] = base;               // total after last entry
}

// ---------------- scan of bucket totals -> exclusive bases bb[0..NB] (wave-shuffle)
__global__ __launch_bounds__(1024) void k_bb(
    const int* __restrict__ tot, int NB, int* __restrict__ bb)
{
    __shared__ int wsum[16];
    int t = threadIdx.x;
    int lane = t & 63, wv = t >> 6;
    int c = (t < NB) ? tot[t] : 0;
    int inc = wave_iscan(c, lane);
    if (lane == 63) wsum[wv] = inc;
    __syncthreads();
    if (t < 16) {
        int s2 = wsum[t];
#pragma unroll
        for (int d = 1; d < 16; d <<= 1) {
            int u = __shfl_up(s2, d, 64);
            if (t >= d) s2 += u;
        }
        wsum[t] = s2;                           // inclusive wave sums
    }
    __syncthreads();
    int base = (wv == 0) ? 0 : wsum[wv - 1];
    int incl = base + inc;
    if (t < NB) bb[t] = incl - c;               // exclusive
    if (t == NB - 1) bb[NB] = incl;
}

// ---------------- P2: bucket-group edges; payload in regs (attr packed f16),
//                  2-pass LDS staging, read-once + coalesced-write-once
__global__ __launch_bounds__(1024) void k_p2(
    const int* __restrict__ ei, long long ne, const float4* __restrict__ attr,
    const int* __restrict__ M, const int* __restrict__ bb, int NB,
    unsigned* __restrict__ sp1, uint2* __restrict__ sattr1)
{
    __shared__ int lcnt[MAXNB];       // per-bucket counts
    __shared__ int excl[MAXNB];       // block-local exclusive base per bucket
    __shared__ int gb[MAXNB];         // global dest base per bucket for this block
    __shared__ int wsum[16];
    __shared__ unsigned sp_st[HALF];  // staged packed sp
    __shared__ uint2   sat_st[HALF];  // staged packed attr
    __shared__ int     gd_st[HALF];   // staged global dest
    int t = threadIdx.x;
    int lane = t & 63, wv = t >> 6;
    const int* row = M + (long long)blockIdx.x * NB;
    gb[t]   = (t < NB) ? (bb[t] + row[t]) : 0;
    lcnt[t] = 0;
    __syncthreads();
    long long beg = (long long)blockIdx.x * CHUNK;
    long long end = beg + CHUNK; if (end > ne) end = ne;
    int nloc = (int)(end - beg);
    // ---- phase A: read edges once, payload in regs, rank via LDS atomics
    unsigned pk8[8]; uint2 a8[8]; int k8[8], r8[8];
#pragma unroll
    for (int j = 0; j < 8; ++j) {
        long long e = beg + t + (long long)j * 1024;
        if (e < end) {
            int s = ei[e];
            int d = ei[ne + e];
            a8[j] = pack4(attr[e]);
            int k = d >> BSH;
            k8[j] = k;
            pk8[j] = (unsigned)s | ((unsigned)(d & (BSZ - 1)) << 20);
            r8[j] = atomicAdd(&lcnt[k], 1);
        } else k8[j] = -1;
    }
    __syncthreads();
    // ---- phase B: wave-shuffle scan of lcnt -> excl
    int c = lcnt[t];
    int inc = wave_iscan(c, lane);
    if (lane == 63) wsum[wv] = inc;
    __syncthreads();
    if (t < 16) {
        int s2 = wsum[t];
#pragma unroll
        for (int d = 1; d < 16; d <<= 1) {
            int u = __shfl_up(s2, d, 64);
            if (t >= d) s2 += u;
        }
        wsum[t] = s2;
    }
    __syncthreads();
    excl[t] = inc - c + ((wv == 0) ? 0 : wsum[wv - 1]);
    __syncthreads();
    int idx8[8];
#pragma unroll
    for (int j = 0; j < 8; ++j)
        idx8[j] = (k8[j] >= 0) ? (excl[k8[j]] + r8[j]) : -1;
    // ---- phases C/D: two staging passes, coalesced global writes
#pragma unroll
    for (int q = 0; q < 2; ++q) {
        int lo = q * HALF;
#pragma unroll
        for (int j = 0; j < 8; ++j) {
            int idx = idx8[j] - lo;
            if (idx8[j] >= 0 && idx >= 0 && idx < HALF) {
                sp_st[idx]  = pk8[j];
                sat_st[idx] = a8[j];
                gd_st[idx]  = gb[k8[j]] + r8[j];
            }
        }
        __syncthreads();
        for (int p = t; p < HALF; p += 1024) {
            int gp = lo + p;
            if (gp < nloc) {
                int gd = gd_st[p];
                sp1[gd]    = sp_st[p];
                sattr1[gd] = sat_st[p];
            }
        }
        __syncthreads();
    }
}

// ---------------- P3: within-bucket counting sort by local dst -> dst-sorted CSR + off[]
__global__ __launch_bounds__(1024) void k_p3(
    const unsigned* __restrict__ sp1, const uint2* __restrict__ sattr1,
    const int* __restrict__ bb, int NB, long long nn,
    unsigned* __restrict__ sp2, uint2* __restrict__ sattr2, int* __restrict__ off)
{
    __shared__ int cnt[BSZ];
    __shared__ int stage[BSZ];
    __shared__ int wsum0;
    int k = blockIdx.x, t = threadIdx.x;
    int lane = t & 63, wv = t >> 6;
    int beg = bb[k], end = bb[k + 1];
    if (t < BSZ) cnt[t] = 0;
    __syncthreads();
    for (int e = beg + t; e < end; e += 1024)
        atomicAdd(&cnt[sp1[e] >> 20], 1);
    __syncthreads();
    if (t < BSZ) {
        int c = cnt[t];
        int inc = wave_iscan(c, lane);
        stage[t] = inc;
        if (lane == 63 && wv == 0) wsum0 = inc;
    }
    __syncthreads();
    if (t < BSZ) {
        int c = cnt[t];
        int incl = stage[t] + ((wv == 1) ? wsum0 : 0);
        int excl = beg + incl - c;
        long long n = (long long)k * BSZ + t;
        if (n < nn) off[n] = excl;
        cnt[t] = excl;                          // becomes scatter counter
    }
    if (k == NB - 1 && t == 0) off[nn] = end;
    __syncthreads();
    for (int e = beg + t; e < end; e += 1024) {
        unsigned pk = sp1[e];
        int ld = pk >> 20;
        int p = atomicAdd(&cnt[ld], 1);
        sp2[p] = pk & 0xFFFFF;
        sattr2[p] = sattr1[e];
    }
}

// ---------------- Layer 0: 16 lanes/node, dim-per-lane, explicit SW-pipelined loop
__global__ __launch_bounds__(256) void k_layer0(
    const __half* __restrict__ xp, long long nn, const int* __restrict__ off,
    const unsigned* __restrict__ sp2, const uint2* __restrict__ sattr2,
    const float* __restrict__ Wec1, const float* __restrict__ bec1,
    const float* __restrict__ Wl, const float* __restrict__ bl,
    __half* __restrict__ hout)
{
    __shared__ float sW1[64], sb1[16], sWl[16 * 17], sbl[16];
    int t = threadIdx.x;
    if (t < 64)  sW1[t] = (t < 48) ? Wec1[t] : 0.f;
    if (t < 16)  sb1[t] = (t < 12) ? bec1[t] : 0.f;
    { int i = t >> 4, j = t & 15;
      sWl[i * 17 + j] = (i < 15 && j < 12) ? Wl[i * 12 + j] : 0.f; }
    if (t < 16)  sbl[t] = (t < 15) ? bl[t] : 0.f;
    __syncthreads();
    int g = t >> 4, l = t & 15;
    long long n = (long long)blockIdx.x * 16 + g;
    if (n >= nn) return;
    int beg = off[n], end = off[n + 1];
    float w0 = sW1[l*4+0], w1 = sW1[l*4+1], w2 = sW1[l*4+2], w3 = sW1[l*4+3];
    float b1 = sb1[l];
    float xn = __half2float(xp[(n << 4) + l]);
    float acc = 0.f;
    int e = beg;
    if (end - beg >= 4) {
        // prologue: stream pairs 0 and 1; gather pair 0
        unsigned s0 = sp2[e],   s1 = sp2[e+1], s2 = sp2[e+2], s3 = sp2[e+3];
        uint2    a0 = sattr2[e], a1 = sattr2[e+1], a2 = sattr2[e+2], a3 = sattr2[e+3];
        float    h0 = gat16(xp, s0, l), h1 = gat16(xp, s1, l);
        // steady state: gather pair1, stream pair2, consume pair0 (loaded last iter)
        for (; e + 5 < end; e += 2) {
            float g2 = gat16(xp, s2, l), g3 = gat16(xp, s3, l);
            unsigned t4 = sp2[e+4], t5 = sp2[e+5];
            uint2    b4 = sattr2[e+4], b5 = sattr2[e+5];
            acc += msgf(h0, a0, w0, w1, w2, w3, b1) + msgf(h1, a1, w0, w1, w2, w3, b1);
            s0 = s2; a0 = a2; h0 = g2;
            s1 = s3; a1 = a3; h1 = g3;
            s2 = t4; a2 = b4; s3 = t5; a3 = b5;
        }
        // drain: consume pair0 (gathered), then pair1 (gather now)
        acc += msgf(h0, a0, w0, w1, w2, w3, b1) + msgf(h1, a1, w0, w1, w2, w3, b1);
        acc += msgf(gat16(xp, s2, l), a2, w0, w1, w2, w3, b1)
             + msgf(gat16(xp, s3, l), a3, w0, w1, w2, w3, b1);
        e += 4;
    }
    for (; e < end; ++e)
        acc += msgf(gat16(xp, sp2[e], l), sattr2[e], w0, w1, w2, w3, b1);
    float v = xn + acc;
    float r = sbl[l];
#pragma unroll
    for (int j = 0; j < 12; ++j) {
        float vj = __shfl(v, j, 16);
        r += vj * sWl[l * 17 + j];
    }
    float o = r > 0.f ? r : expm1f(r);
    hout[(n << 4) + l] = __float2half_rn((l < 15) ? o : 0.f);
}

// ---------------- Layers 1/2: folded edge transform, explicit SW-pipelined loop
template<bool POOL, bool STORE>
__global__ __launch_bounds__(256) void k_layerK(
    const __half* __restrict__ h, long long nn, const int* __restrict__ off,
    const unsigned* __restrict__ sp2, const uint2* __restrict__ sattr2,
    const float* __restrict__ Wec1, const float* __restrict__ bec1,
    const float* __restrict__ Wec2, const float* __restrict__ bec2,
    const float* __restrict__ Wl, const float* __restrict__ bl,
    __half* __restrict__ hout, const int* __restrict__ batch, float* __restrict__ pooled)
{
    __shared__ float sW12[64], sb12[16], sWl[16 * 17], sbl[16];
    int t = threadIdx.x;
    if (t < 64) {                        // fold W12 = Wec2 @ Wec1 (15x4, row 15 zero)
        int i = t >> 2, kk = t & 3;
        float a = 0.f;
        if (i < 15) {
#pragma unroll
            for (int j = 0; j < 12; ++j) a += Wec2[i*12+j] * Wec1[j*4+kk];
        }
        sW12[t] = a;
    }
    if (t < 16) {                        // b12 = Wec2 @ bec1 + bec2
        float a = 0.f;
        if (t < 15) {
            a = bec2[t];
#pragma unroll
            for (int j = 0; j < 12; ++j) a += Wec2[t*12+j] * bec1[j];
        }
        sb12[t] = a;
    }
    { int i = t >> 4, j = t & 15;
      sWl[i * 17 + j] = (i < 15 && j < 15) ? Wl[i * 15 + j] : 0.f; }
    if (t < 16) sbl[t] = (t < 15) ? bl[t] : 0.f;
    __syncthreads();
    int g = t >> 4, l = t & 15;
    long long n = (long long)blockIdx.x * 16 + g;
    if (n >= nn) return;
    int beg = off[n], end = off[n + 1];
    float w0 = sW12[l*4+0], w1 = sW12[l*4+1], w2 = sW12[l*4+2], w3 = sW12[l*4+3];
    float b12 = sb12[l];
    float hn = __half2float(h[(n << 4) + l]);
    float acc = 0.f;
    int e = beg;
    if (end - beg >= 4) {
        unsigned s0 = sp2[e],   s1 = sp2[e+1], s2 = sp2[e+2], s3 = sp2[e+3];
        uint2    a0 = sattr2[e], a1 = sattr2[e+1], a2 = sattr2[e+2], a3 = sattr2[e+3];
        float    h0 = gat16(h, s0, l), h1 = gat16(h, s1, l);
        for (; e + 5 < end; e += 2) {
            float g2 = gat16(h, s2, l), g3 = gat16(h, s3, l);
            unsigned t4 = sp2[e+4], t5 = sp2[e+5];
            uint2    b4 = sattr2[e+4], b5 = sattr2[e+5];
            acc += msgf(h0, a0, w0, w1, w2, w3, b12) + msgf(h1, a1, w0, w1, w2, w3, b12);
            s0 = s2; a0 = a2; h0 = g2;
            s1 = s3; a1 = a3; h1 = g3;
            s2 = t4; a2 = b4; s3 = t5; a3 = b5;
        }
        acc += msgf(h0, a0, w0, w1, w2, w3, b12) + msgf(h1, a1, w0, w1, w2, w3, b12);
        acc += msgf(gat16(h, s2, l), a2, w0, w1, w2, w3, b12)
             + msgf(gat16(h, s3, l), a3, w0, w1, w2, w3, b12);
        e += 4;
    }
    for (; e < end; ++e)
        acc += msgf(gat16(h, sp2[e], l), sattr2[e], w0, w1, w2, w3, b12);
    float v = hn + acc;
    float r = sbl[l];
#pragma unroll
    for (int j = 0; j < 15; ++j) {
        float vj = __shfl(v, j, 16);
        r += vj * sWl[l * 17 + j];
    }
    float o = r > 0.f ? r : expm1f(r);
    if (STORE) hout[(n << 4) + l] = __float2half_rn((l < 15) ? o : 0.f);
    if (POOL && l < 15) atomicAdd(&pooled[(long long)batch[n] * HS + l], o);
}

// ---------------- Head
__global__ __launch_bounds__(256) void k_head(
    const float* __restrict__ pooled, long long ng,
    const float* __restrict__ Wo1, const float* __restrict__ bo1,
    const float* __restrict__ Wo2, const float* __restrict__ bo2,
    float* __restrict__ out)
{
    long long g = (long long)blockIdx.x * 256 + threadIdx.x;
    if (g >= ng) return;
    float p[15], m[15];
#pragma unroll
    for (int j = 0; j < 15; ++j) p[j] = pooled[g * HS + j];
#pragma unroll
    for (int i = 0; i < 15; ++i) {
        float acc = bo1[i];
#pragma unroll
        for (int j = 0; j < 15; ++j) acc += p[j] * Wo1[i * 15 + j];
        m[i] = acc;
    }
#pragma unroll
    for (int i = 0; i < 2; ++i) {
        float acc = bo2[i];
#pragma unroll
        for (int j = 0; j < 15; ++j) acc += m[j] * Wo2[i * 15 + j];
        out[g * 2 + i] = acc;
    }
}

extern "C" void kernel_launch(void* const* d_in, const int* in_sizes, int n_in,
                              void* d_out, int out_size, void* d_ws, size_t ws_size,
                              hipStream_t stream)
{
    const float* x    = (const float*)d_in[0];
    const int*   ei   = (const int*)d_in[1];
    const float* attr = (const float*)d_in[2];
    const int*   batch= (const int*)d_in[3];
    const float* Wec1 = (const float*)d_in[4];
    const float* bec1 = (const float*)d_in[5];
    const float* Wec2 = (const float*)d_in[6];
    const float* bec2 = (const float*)d_in[7];
    const float* Wl0  = (const float*)d_in[8];
    const float* bl0  = (const float*)d_in[9];
    const float* Wl1  = (const float*)d_in[10];
    const float* bl1  = (const float*)d_in[11];
    const float* Wl2  = (const float*)d_in[12];
    const float* bl2  = (const float*)d_in[13];
    const float* Wo1  = (const float*)d_in[14];
    const float* bo1  = (const float*)d_in[15];
    const float* Wo2  = (const float*)d_in[16];
    const float* bo2  = (const float*)d_in[17];

    const long long nn = in_sizes[0] / D_NODE;   // 100000
    const long long ne = in_sizes[1] / 2;        // 3200000
    const long long ng = out_size / 2;           // 1024

    const int NB   = (int)((nn + BSZ - 1) >> BSH);           // 782
    const int nblk = (int)((ne + CHUNK - 1) / CHUNK);        // 391

    // ---- workspace layout ----
    char* w = (char*)d_ws;
    uint2*    sattr1 = (uint2*)w;                 w += (size_t)ne * sizeof(uint2);
    unsigned* sp1    = (unsigned*)w;              w += (size_t)ne * sizeof(unsigned);
    uint2*    sattr2 = (uint2*)w;                 w += (size_t)ne * sizeof(uint2);
    unsigned* sp2    = (unsigned*)w;              w += (size_t)ne * sizeof(unsigned);
    int*      M      = (int*)w;                   w += (size_t)nblk * NB * sizeof(int);
    int*      tot    = (int*)w;                   w += (size_t)NB * sizeof(int);
    int*      bb     = (int*)w;                   w += ((size_t)NB + 1) * sizeof(int);
    int*      off    = (int*)w;                   w += ((size_t)nn + 1) * sizeof(int);
    w = (char*)(((uintptr_t)w + 15) & ~(uintptr_t)15);
    __half*   xp     = (__half*)w;                w += (size_t)nn * HS * sizeof(__half);
    // overlay: hA/hB/pooled reuse the sattr1 region (dead after k_p3)
    __half*   hA     = (__half*)sattr1;
    __half*   hB     = hA + (size_t)nn * HS;
    float*    pooled = (float*)(hB + (size_t)nn * HS);
    float*    out    = (float*)d_out;

    // ---- x -> fp16 padded table (independent of sort) ----
    k_xcvt<<<(int)((nn * HS + 255) / 256), 256, 0, stream>>>(x, nn, xp);

    // ---- build full dst-sorted CSR (shared by all 3 layers) ----
    k_p1<<<nblk, 1024, 0, stream>>>(ei, ne, NB, M);
    k_colscan<<<NB, 256, 0, stream>>>(M, nblk, NB, tot);
    k_bb<<<1, 1024, 0, stream>>>(tot, NB, bb);
    k_p2<<<nblk, 1024, 0, stream>>>(ei, ne, (const float4*)attr, M, bb, NB, sp1, sattr1);
    k_p3<<<NB, 1024, 0, stream>>>(sp1, sattr1, bb, NB, nn, sp2, sattr2, off);

    // ---- layers (16 lanes per node, dim-per-lane; SW-pipelined gather loop) ----
    const int lblk = (int)((nn + 15) / 16);      // 6250
    k_layer0<<<lblk, 256, 0, stream>>>(xp, nn, off, sp2, sattr2, Wec1, bec1, Wl0, bl0, hA);
    k_layerK<false, true><<<lblk, 256, 0, stream>>>(hA, nn, off, sp2, sattr2,
        Wec1, bec1, Wec2, bec2, Wl1, bl1, hB, nullptr, nullptr);
    hipMemsetAsync(pooled, 0, (size_t)ng * HS * sizeof(float), stream);
    k_layerK<true, false><<<lblk, 256, 0, stream>>>(hB, nn, off, sp2, sattr2,
        Wec1, bec1, Wec2, bec2, Wl2, bl2, nullptr, batch, pooled);

    // ---- head ----
    k_head<<<(int)((ng + 255) / 256), 256, 0, stream>>>(pooled, ng, Wo1, bo1, Wo2, bo2, out);
}

// Round 18
// 285.771 us; speedup vs baseline: 1.0067x; 1.0067x over previous
//
#include <hip/hip_runtime.h>
#include <hip/hip_fp16.h>
#include <math.h>

#define D_NODE 12
#define HS     16     // padded row stride for hidden buffers (elements)
#define BSH    7      // bucket shift: 128 nodes per bucket
#define BSZ    128
#define CHUNK  8192   // edges per partition block (P1/P2)
#define HALF   4096   // staging half-chunk (P2)
#define MAXNB  1024   // max buckets supported (nn <= 131072)
#define ECAP   1024   // per-block edge-window LDS capacity (layer kernels)

__device__ __forceinline__ int wave_iscan(int v, int lane) {
#pragma unroll
    for (int d = 1; d < 64; d <<= 1) {
        int u = __shfl_up(v, d, 64);
        if (lane >= d) v += u;
    }
    return v;
}

__device__ __forceinline__ uint2 pack4(float4 a) {
    __half2 lo = __floats2half2_rn(a.x, a.y);
    __half2 hi = __floats2half2_rn(a.z, a.w);
    uint2 r;
    r.x = *reinterpret_cast<unsigned*>(&lo);
    r.y = *reinterpret_cast<unsigned*>(&hi);
    return r;
}

__device__ __forceinline__ float4 unpack4(unsigned ux, unsigned uy) {
    __half2 lo = *reinterpret_cast<__half2*>(&ux);
    __half2 hi = *reinterpret_cast<__half2*>(&uy);
    float2 f0 = __half22float2(lo), f1 = __half22float2(hi);
    return make_float4(f0.x, f0.y, f1.x, f1.y);
}

__device__ __forceinline__ float gat16(const __half* __restrict__ tab, unsigned s, int l) {
    return __half2float(tab[((long long)s << 4) + l]);
}

__device__ __forceinline__ float msgf(float hs, uint2 at,
                                      float w0, float w1, float w2, float w3, float b) {
    float4 a = unpack4(at.x, at.y);
    return fmaxf(hs + b + w0 * a.x + w1 * a.y + w2 * a.z + w3 * a.w, 0.f);
}

// ---------------- convert x to padded fp16 table [nn][16]
__global__ __launch_bounds__(256) void k_xcvt(
    const float* __restrict__ x, long long nn, __half* __restrict__ xp)
{
    long long idx = (long long)blockIdx.x * 256 + threadIdx.x;
    if (idx >= nn * HS) return;
    long long n = idx >> 4;
    int l = (int)(idx & 15);
    xp[idx] = __float2half_rn((l < D_NODE) ? x[n * D_NODE + l] : 0.f);
}

// ---------------- P1: per-(block,bucket) histogram of dst
__global__ __launch_bounds__(1024) void k_p1(
    const int* __restrict__ ei, long long ne, int NB, int* __restrict__ M)
{
    __shared__ int cnt[MAXNB];
    int t = threadIdx.x;
    for (int k = t; k < NB; k += 1024) cnt[k] = 0;
    __syncthreads();
    long long beg = (long long)blockIdx.x * CHUNK;
    long long end = beg + CHUNK; if (end > ne) end = ne;
    for (long long e = beg + t; e < end; e += 1024)
        atomicAdd(&cnt[ei[ne + e] >> BSH], 1);
    __syncthreads();
    int* row = M + (long long)blockIdx.x * NB;
    for (int k = t; k < NB; k += 1024) row[k] = cnt[k];
}

// ---------------- per-bucket column scan over blocks (wave-shuffle scan)
__global__ __launch_bounds__(256) void k_colscan(
    int* __restrict__ M, int nblk, int NB, int* __restrict__ tot)
{
    __shared__ int wsum[4];
    int k = blockIdx.x;
    int t = threadIdx.x;
    int lane = t & 63, wv = t >> 6;
    int v[4]; int s = 0;                       // supports nblk <= 1024
#pragma unroll
    for (int j = 0; j < 4; ++j) {
        int b = t * 4 + j;
        v[j] = (b < nblk) ? M[(long long)b * NB + k] : 0;
        s += v[j];
    }
    int inc = wave_iscan(s, lane);
    if (lane == 63) wsum[wv] = inc;
    __syncthreads();
    int base = inc - s;
#pragma unroll
    for (int j = 0; j < 4; ++j) { if (j < wv) base += wsum[j]; }
#pragma unroll
    for (int j = 0; j < 4; ++j) {
        int b = t * 4 + j;
        if (b < nblk) { M[(long long)b * NB + k] = base; base += v[j]; }
    }
    if (t == 255) tot[k] = base;               // total after last entry
}

// ---------------- scan of bucket totals -> exclusive bases bb[0..NB] (wave-shuffle)
__global__ __launch_bounds__(1024) void k_bb(
    const int* __restrict__ tot, int NB, int* __restrict__ bb)
{
    __shared__ int wsum[16];
    int t = threadIdx.x;
    int lane = t & 63, wv = t >> 6;
    int c = (t < NB) ? tot[t] : 0;
    int inc = wave_iscan(c, lane);
    if (lane == 63) wsum[wv] = inc;
    __syncthreads();
    if (t < 16) {
        int s2 = wsum[t];
#pragma unroll
        for (int d = 1; d < 16; d <<= 1) {
            int u = __shfl_up(s2, d, 64);
            if (t >= d) s2 += u;
        }
        wsum[t] = s2;                           // inclusive wave sums
    }
    __syncthreads();
    int base = (wv == 0) ? 0 : wsum[wv - 1];
    int incl = base + inc;
    if (t < NB) bb[t] = incl - c;               // exclusive
    if (t == NB - 1) bb[NB] = incl;
}

// ---------------- P2: bucket-group edges; payload in regs (attr packed f16),
//                  2-pass LDS staging, read-once + coalesced-write-once
__global__ __launch_bounds__(1024) void k_p2(
    const int* __restrict__ ei, long long ne, const float4* __restrict__ attr,
    const int* __restrict__ M, const int* __restrict__ bb, int NB,
    unsigned* __restrict__ sp1, uint2* __restrict__ sattr1)
{
    __shared__ int lcnt[MAXNB];       // per-bucket counts
    __shared__ int excl[MAXNB];       // block-local exclusive base per bucket
    __shared__ int gb[MAXNB];         // global dest base per bucket for this block
    __shared__ int wsum[16];
    __shared__ unsigned sp_st[HALF];  // staged packed sp
    __shared__ uint2   sat_st[HALF];  // staged packed attr
    __shared__ int     gd_st[HALF];   // staged global dest
    int t = threadIdx.x;
    int lane = t & 63, wv = t >> 6;
    const int* row = M + (long long)blockIdx.x * NB;
    gb[t]   = (t < NB) ? (bb[t] + row[t]) : 0;
    lcnt[t] = 0;
    __syncthreads();
    long long beg = (long long)blockIdx.x * CHUNK;
    long long end = beg + CHUNK; if (end > ne) end = ne;
    int nloc = (int)(end - beg);
    // ---- phase A: read edges once, payload in regs, rank via LDS atomics
    unsigned pk8[8]; uint2 a8[8]; int k8[8], r8[8];
#pragma unroll
    for (int j = 0; j < 8; ++j) {
        long long e = beg + t + (long long)j * 1024;
        if (e < end) {
            int s = ei[e];
            int d = ei[ne + e];
            a8[j] = pack4(attr[e]);
            int k = d >> BSH;
            k8[j] = k;
            pk8[j] = (unsigned)s | ((unsigned)(d & (BSZ - 1)) << 20);
            r8[j] = atomicAdd(&lcnt[k], 1);
        } else k8[j] = -1;
    }
    __syncthreads();
    // ---- phase B: wave-shuffle scan of lcnt -> excl
    int c = lcnt[t];
    int inc = wave_iscan(c, lane);
    if (lane == 63) wsum[wv] = inc;
    __syncthreads();
    if (t < 16) {
        int s2 = wsum[t];
#pragma unroll
        for (int d = 1; d < 16; d <<= 1) {
            int u = __shfl_up(s2, d, 64);
            if (t >= d) s2 += u;
        }
        wsum[t] = s2;
    }
    __syncthreads();
    excl[t] = inc - c + ((wv == 0) ? 0 : wsum[wv - 1]);
    __syncthreads();
    int idx8[8];
#pragma unroll
    for (int j = 0; j < 8; ++j)
        idx8[j] = (k8[j] >= 0) ? (excl[k8[j]] + r8[j]) : -1;
    // ---- phases C/D: two staging passes, coalesced global writes
#pragma unroll
    for (int q = 0; q < 2; ++q) {
        int lo = q * HALF;
#pragma unroll
        for (int j = 0; j < 8; ++j) {
            int idx = idx8[j] - lo;
            if (idx8[j] >= 0 && idx >= 0 && idx < HALF) {
                sp_st[idx]  = pk8[j];
                sat_st[idx] = a8[j];
                gd_st[idx]  = gb[k8[j]] + r8[j];
            }
        }
        __syncthreads();
        for (int p = t; p < HALF; p += 1024) {
            int gp = lo + p;
            if (gp < nloc) {
                int gd = gd_st[p];
                sp1[gd]    = sp_st[p];
                sattr1[gd] = sat_st[p];
            }
        }
        __syncthreads();
    }
}

// ---------------- P3: within-bucket counting sort by local dst -> dst-sorted CSR + off[]
__global__ __launch_bounds__(1024) void k_p3(
    const unsigned* __restrict__ sp1, const uint2* __restrict__ sattr1,
    const int* __restrict__ bb, int NB, long long nn,
    unsigned* __restrict__ sp2, uint2* __restrict__ sattr2, int* __restrict__ off)
{
    __shared__ int cnt[BSZ];
    __shared__ int stage[BSZ];
    __shared__ int wsum0;
    int k = blockIdx.x, t = threadIdx.x;
    int lane = t & 63, wv = t >> 6;
    int beg = bb[k], end = bb[k + 1];
    if (t < BSZ) cnt[t] = 0;
    __syncthreads();
    for (int e = beg + t; e < end; e += 1024)
        atomicAdd(&cnt[sp1[e] >> 20], 1);
    __syncthreads();
    if (t < BSZ) {
        int c = cnt[t];
        int inc = wave_iscan(c, lane);
        stage[t] = inc;
        if (lane == 63 && wv == 0) wsum0 = inc;
    }
    __syncthreads();
    if (t < BSZ) {
        int c = cnt[t];
        int incl = stage[t] + ((wv == 1) ? wsum0 : 0);
        int excl = beg + incl - c;
        long long n = (long long)k * BSZ + t;
        if (n < nn) off[n] = excl;
        cnt[t] = excl;                          // becomes scatter counter
    }
    if (k == NB - 1 && t == 0) off[nn] = end;
    __syncthreads();
    for (int e = beg + t; e < end; e += 1024) {
        unsigned pk = sp1[e];
        int ld = pk >> 20;
        int p = atomicAdd(&cnt[ld], 1);
        sp2[p] = pk & 0xFFFFF;
        sattr2[p] = sattr1[e];
    }
}

// ---------------- Layer 0: 16 lanes/node; block edge window staged in LDS
__global__ __launch_bounds__(256) void k_layer0(
    const __half* __restrict__ xp, long long nn, const int* __restrict__ off,
    const unsigned* __restrict__ sp2, const uint2* __restrict__ sattr2,
    const float* __restrict__ Wec1, const float* __restrict__ bec1,
    const float* __restrict__ Wl, const float* __restrict__ bl,
    __half* __restrict__ hout)
{
    __shared__ float sW1[64], sb1[16], sWl[16 * 17], sbl[16];
    __shared__ unsigned ssp[ECAP];
    __shared__ uint2   sat[ECAP];
    int t = threadIdx.x;
    if (t < 64)  sW1[t] = (t < 48) ? Wec1[t] : 0.f;
    if (t < 16)  sb1[t] = (t < 12) ? bec1[t] : 0.f;
    { int i = t >> 4, j = t & 15;
      sWl[i * 17 + j] = (i < 15 && j < 12) ? Wl[i * 12 + j] : 0.f; }
    if (t < 16)  sbl[t] = (t < 15) ? bl[t] : 0.f;
    long long nb0 = (long long)blockIdx.x * 16;
    long long nbe = nb0 + 16; if (nbe > nn) nbe = nn;
    int eb = off[nb0];
    int ee = off[nbe];
    int nblk_e = ee - eb;
    bool lds_ok = (nblk_e <= ECAP);
    if (lds_ok) {
        for (int i = t; i < nblk_e; i += 256) {   // coalesced stream staging (read once)
            ssp[i] = sp2[eb + i];
            sat[i] = sattr2[eb + i];
        }
    }
    __syncthreads();
    int g = t >> 4, l = t & 15;
    long long n = nb0 + g;
    if (n >= nn) return;
    int beg = off[n], end = off[n + 1];
    float w0 = sW1[l*4+0], w1 = sW1[l*4+1], w2 = sW1[l*4+2], w3 = sW1[l*4+3];
    float b1 = sb1[l];
    float xn = __half2float(xp[(n << 4) + l]);
    float acc = 0.f;
    if (lds_ok) {
        for (int e = beg - eb, eE = end - eb; e < eE; ++e) {
            unsigned s = ssp[e];              // 16-lane broadcast, free
            uint2 at = sat[e];
            acc += msgf(gat16(xp, s, l), at, w0, w1, w2, w3, b1);
        }
    } else {
        for (int e = beg; e < end; ++e)
            acc += msgf(gat16(xp, sp2[e], l), sattr2[e], w0, w1, w2, w3, b1);
    }
    float v = xn + acc;
    float r = sbl[l];
#pragma unroll
    for (int j = 0; j < 12; ++j) {
        float vj = __shfl(v, j, 16);
        r += vj * sWl[l * 17 + j];
    }
    float o = r > 0.f ? r : expm1f(r);
    hout[(n << 4) + l] = __float2half_rn((l < 15) ? o : 0.f);
}

// ---------------- Layers 1/2: folded edge transform; block edge window staged in LDS
template<bool POOL, bool STORE>
__global__ __launch_bounds__(256) void k_layerK(
    const __half* __restrict__ h, long long nn, const int* __restrict__ off,
    const unsigned* __restrict__ sp2, const uint2* __restrict__ sattr2,
    const float* __restrict__ Wec1, const float* __restrict__ bec1,
    const float* __restrict__ Wec2, const float* __restrict__ bec2,
    const float* __restrict__ Wl, const float* __restrict__ bl,
    __half* __restrict__ hout, const int* __restrict__ batch, float* __restrict__ pooled)
{
    __shared__ float sW12[64], sb12[16], sWl[16 * 17], sbl[16];
    __shared__ unsigned ssp[ECAP];
    __shared__ uint2   sat[ECAP];
    int t = threadIdx.x;
    if (t < 64) {                        // fold W12 = Wec2 @ Wec1 (15x4, row 15 zero)
        int i = t >> 2, kk = t & 3;
        float a = 0.f;
        if (i < 15) {
#pragma unroll
            for (int j = 0; j < 12; ++j) a += Wec2[i*12+j] * Wec1[j*4+kk];
        }
        sW12[t] = a;
    }
    if (t < 16) {                        // b12 = Wec2 @ bec1 + bec2
        float a = 0.f;
        if (t < 15) {
            a = bec2[t];
#pragma unroll
            for (int j = 0; j < 12; ++j) a += Wec2[t*12+j] * bec1[j];
        }
        sb12[t] = a;
    }
    { int i = t >> 4, j = t & 15;
      sWl[i * 17 + j] = (i < 15 && j < 15) ? Wl[i * 15 + j] : 0.f; }
    if (t < 16) sbl[t] = (t < 15) ? bl[t] : 0.f;
    long long nb0 = (long long)blockIdx.x * 16;
    long long nbe = nb0 + 16; if (nbe > nn) nbe = nn;
    int eb = off[nb0];
    int ee = off[nbe];
    int nblk_e = ee - eb;
    bool lds_ok = (nblk_e <= ECAP);
    if (lds_ok) {
        for (int i = t; i < nblk_e; i += 256) {
            ssp[i] = sp2[eb + i];
            sat[i] = sattr2[eb + i];
        }
    }
    __syncthreads();
    int g = t >> 4, l = t & 15;
    long long n = nb0 + g;
    if (n >= nn) return;
    int beg = off[n], end = off[n + 1];
    float w0 = sW12[l*4+0], w1 = sW12[l*4+1], w2 = sW12[l*4+2], w3 = sW12[l*4+3];
    float b12 = sb12[l];
    float hn = __half2float(h[(n << 4) + l]);
    float acc = 0.f;
    if (lds_ok) {
        for (int e = beg - eb, eE = end - eb; e < eE; ++e) {
            unsigned s = ssp[e];
            uint2 at = sat[e];
            acc += msgf(gat16(h, s, l), at, w0, w1, w2, w3, b12);
        }
    } else {
        for (int e = beg; e < end; ++e)
            acc += msgf(gat16(h, sp2[e], l), sattr2[e], w0, w1, w2, w3, b12);
    }
    float v = hn + acc;
    float r = sbl[l];
#pragma unroll
    for (int j = 0; j < 15; ++j) {
        float vj = __shfl(v, j, 16);
        r += vj * sWl[l * 17 + j];
    }
    float o = r > 0.f ? r : expm1f(r);
    if (STORE) hout[(n << 4) + l] = __float2half_rn((l < 15) ? o : 0.f);
    if (POOL && l < 15) atomicAdd(&pooled[(long long)batch[n] * HS + l], o);
}

// ---------------- Head
__global__ __launch_bounds__(256) void k_head(
    const float* __restrict__ pooled, long long ng,
    const float* __restrict__ Wo1, const float* __restrict__ bo1,
    const float* __restrict__ Wo2, const float* __restrict__ bo2,
    float* __restrict__ out)
{
    long long g = (long long)blockIdx.x * 256 + threadIdx.x;
    if (g >= ng) return;
    float p[15], m[15];
#pragma unroll
    for (int j = 0; j < 15; ++j) p[j] = pooled[g * HS + j];
#pragma unroll
    for (int i = 0; i < 15; ++i) {
        float acc = bo1[i];
#pragma unroll
        for (int j = 0; j < 15; ++j) acc += p[j] * Wo1[i * 15 + j];
        m[i] = acc;
    }
#pragma unroll
    for (int i = 0; i < 2; ++i) {
        float acc = bo2[i];
#pragma unroll
        for (int j = 0; j < 15; ++j) acc += m[j] * Wo2[i * 15 + j];
        out[g * 2 + i] = acc;
    }
}

extern "C" void kernel_launch(void* const* d_in, const int* in_sizes, int n_in,
                              void* d_out, int out_size, void* d_ws, size_t ws_size,
                              hipStream_t stream)
{
    const float* x    = (const float*)d_in[0];
    const int*   ei   = (const int*)d_in[1];
    const float* attr = (const float*)d_in[2];
    const int*   batch= (const int*)d_in[3];
    const float* Wec1 = (const float*)d_in[4];
    const float* bec1 = (const float*)d_in[5];
    const float* Wec2 = (const float*)d_in[6];
    const float* bec2 = (const float*)d_in[7];
    const float* Wl0  = (const float*)d_in[8];
    const float* bl0  = (const float*)d_in[9];
    const float* Wl1  = (const float*)d_in[10];
    const float* bl1  = (const float*)d_in[11];
    const float* Wl2  = (const float*)d_in[12];
    const float* bl2  = (const float*)d_in[13];
    const float* Wo1  = (const float*)d_in[14];
    const float* bo1  = (const float*)d_in[15];
    const float* Wo2  = (const float*)d_in[16];
    const float* bo2  = (const float*)d_in[17];

    const long long nn = in_sizes[0] / D_NODE;   // 100000
    const long long ne = in_sizes[1] / 2;        // 3200000
    const long long ng = out_size / 2;           // 1024

    const int NB   = (int)((nn + BSZ - 1) >> BSH);           // 782
    const int nblk = (int)((ne + CHUNK - 1) / CHUNK);        // 391

    // ---- workspace layout ----
    char* w = (char*)d_ws;
    uint2*    sattr1 = (uint2*)w;                 w += (size_t)ne * sizeof(uint2);
    unsigned* sp1    = (unsigned*)w;              w += (size_t)ne * sizeof(unsigned);
    uint2*    sattr2 = (uint2*)w;                 w += (size_t)ne * sizeof(uint2);
    unsigned* sp2    = (unsigned*)w;              w += (size_t)ne * sizeof(unsigned);
    int*      M      = (int*)w;                   w += (size_t)nblk * NB * sizeof(int);
    int*      tot    = (int*)w;                   w += (size_t)NB * sizeof(int);
    int*      bb     = (int*)w;                   w += ((size_t)NB + 1) * sizeof(int);
    int*      off    = (int*)w;                   w += ((size_t)nn + 1) * sizeof(int);
    w = (char*)(((uintptr_t)w + 15) & ~(uintptr_t)15);
    __half*   xp     = (__half*)w;                w += (size_t)nn * HS * sizeof(__half);
    // overlay: hA/hB/pooled reuse the sattr1 region (dead after k_p3)
    __half*   hA     = (__half*)sattr1;
    __half*   hB     = hA + (size_t)nn * HS;
    float*    pooled = (float*)(hB + (size_t)nn * HS);
    float*    out    = (float*)d_out;

    // ---- x -> fp16 padded table (independent of sort) ----
    k_xcvt<<<(int)((nn * HS + 255) / 256), 256, 0, stream>>>(x, nn, xp);

    // ---- build full dst-sorted CSR (shared by all 3 layers) ----
    k_p1<<<nblk, 1024, 0, stream>>>(ei, ne, NB, M);
    k_colscan<<<NB, 256, 0, stream>>>(M, nblk, NB, tot);
    k_bb<<<1, 1024, 0, stream>>>(tot, NB, bb);
    k_p2<<<nblk, 1024, 0, stream>>>(ei, ne, (const float4*)attr, M, bb, NB, sp1, sattr1);
    k_p3<<<NB, 1024, 0, stream>>>(sp1, sattr1, bb, NB, nn, sp2, sattr2, off);

    // ---- layers (16 lanes per node; block edge window staged in LDS) ----
    const int lblk = (int)((nn + 15) / 16);      // 6250
    k_layer0<<<lblk, 256, 0, stream>>>(xp, nn, off, sp2, sattr2, Wec1, bec1, Wl0, bl0, hA);
    k_layerK<false, true><<<lblk, 256, 0, stream>>>(hA, nn, off, sp2, sattr2,
        Wec1, bec1, Wec2, bec2, Wl1, bl1, hB, nullptr, nullptr);
    hipMemsetAsync(pooled, 0, (size_t)ng * HS * sizeof(float), stream);
    k_layerK<true, false><<<lblk, 256, 0, stream>>>(hB, nn, off, sp2, sattr2,
        Wec1, bec1, Wec2, bec2, Wl2, bl2, nullptr, batch, pooled);

    // ---- head ----
    k_head<<<(int)((ng + 255) / 256), 256, 0, stream>>>(pooled, ng, Wo1, bo1, Wo2, bo2, out);
}

// Round 19
// 264.414 us; speedup vs baseline: 1.0880x; 1.0808x over previous
//
#include <hip/hip_runtime.h>
#include <hip/hip_fp16.h>
#include <math.h>

#define D_NODE 12
#define HS     16     // padded row stride for hidden buffers (elements)
#define BSH    7      // bucket shift: 128 nodes per bucket
#define BSZ    128
#define CHUNK  8192   // edges per partition block (P1/P2)
#define HALF   4096   // staging half-chunk (P2)
#define MAXNB  1024   // max buckets supported (nn <= 131072)

__device__ __forceinline__ int wave_iscan(int v, int lane) {
#pragma unroll
    for (int d = 1; d < 64; d <<= 1) {
        int u = __shfl_up(v, d, 64);
        if (lane >= d) v += u;
    }
    return v;
}

__device__ __forceinline__ uint2 pack4(float4 a) {
    __half2 lo = __floats2half2_rn(a.x, a.y);
    __half2 hi = __floats2half2_rn(a.z, a.w);
    uint2 r;
    r.x = *reinterpret_cast<unsigned*>(&lo);
    r.y = *reinterpret_cast<unsigned*>(&hi);
    return r;
}

__device__ __forceinline__ float4 unpack4(uint2 u) {
    __half2 lo = *reinterpret_cast<__half2*>(&u.x);
    __half2 hi = *reinterpret_cast<__half2*>(&u.y);
    float2 f0 = __half22float2(lo), f1 = __half22float2(hi);
    return make_float4(f0.x, f0.y, f1.x, f1.y);
}

// ---------------- convert x to padded fp16 table [nn][16]
__global__ __launch_bounds__(256) void k_xcvt(
    const float* __restrict__ x, long long nn, __half* __restrict__ xp)
{
    long long idx = (long long)blockIdx.x * 256 + threadIdx.x;
    if (idx >= nn * HS) return;
    long long n = idx >> 4;
    int l = (int)(idx & 15);
    xp[idx] = __float2half_rn((l < D_NODE) ? x[n * D_NODE + l] : 0.f);
}

// ---------------- P1: per-(block,bucket) histogram of dst
__global__ __launch_bounds__(1024) void k_p1(
    const int* __restrict__ ei, long long ne, int NB, int* __restrict__ M)
{
    __shared__ int cnt[MAXNB];
    int t = threadIdx.x;
    for (int k = t; k < NB; k += 1024) cnt[k] = 0;
    __syncthreads();
    long long beg = (long long)blockIdx.x * CHUNK;
    long long end = beg + CHUNK; if (end > ne) end = ne;
    for (long long e = beg + t; e < end; e += 1024)
        atomicAdd(&cnt[ei[ne + e] >> BSH], 1);
    __syncthreads();
    int* row = M + (long long)blockIdx.x * NB;
    for (int k = t; k < NB; k += 1024) row[k] = cnt[k];
}

// ---------------- per-bucket column scan over blocks (wave-shuffle scan)
__global__ __launch_bounds__(256) void k_colscan(
    int* __restrict__ M, int nblk, int NB, int* __restrict__ tot)
{
    __shared__ int wsum[4];
    int k = blockIdx.x;
    int t = threadIdx.x;
    int lane = t & 63, wv = t >> 6;
    int v[4]; int s = 0;                       // supports nblk <= 1024
#pragma unroll
    for (int j = 0; j < 4; ++j) {
        int b = t * 4 + j;
        v[j] = (b < nblk) ? M[(long long)b * NB + k] : 0;
        s += v[j];
    }
    int inc = wave_iscan(s, lane);
    if (lane == 63) wsum[wv] = inc;
    __syncthreads();
    int base = inc - s;
#pragma unroll
    for (int j = 0; j < 4; ++j) { if (j < wv) base += wsum[j]; }
#pragma unroll
    for (int j = 0; j < 4; ++j) {
        int b = t * 4 + j;
        if (b < nblk) { M[(long long)b * NB + k] = base; base += v[j]; }
    }
    if (t == 255) tot[k] = base;               // total after last entry
}

// ---------------- scan of bucket totals -> exclusive bases bb[0..NB] (wave-shuffle)
__global__ __launch_bounds__(1024) void k_bb(
    const int* __restrict__ tot, int NB, int* __restrict__ bb)
{
    __shared__ int wsum[16];
    int t = threadIdx.x;
    int lane = t & 63, wv = t >> 6;
    int c = (t < NB) ? tot[t] : 0;
    int inc = wave_iscan(c, lane);
    if (lane == 63) wsum[wv] = inc;
    __syncthreads();
    if (t < 16) {
        int s2 = wsum[t];
#pragma unroll
        for (int d = 1; d < 16; d <<= 1) {
            int u = __shfl_up(s2, d, 64);
            if (t >= d) s2 += u;
        }
        wsum[t] = s2;                           // inclusive wave sums
    }
    __syncthreads();
    int base = (wv == 0) ? 0 : wsum[wv - 1];
    int incl = base + inc;
    if (t < NB) bb[t] = incl - c;               // exclusive
    if (t == NB - 1) bb[NB] = incl;
}

// ---------------- P2: bucket-group edges; payload in regs (attr packed f16),
//                  2-pass LDS staging, read-once + coalesced-write-once
__global__ __launch_bounds__(1024) void k_p2(
    const int* __restrict__ ei, long long ne, const float4* __restrict__ attr,
    const int* __restrict__ M, const int* __restrict__ bb, int NB,
    unsigned* __restrict__ sp1, uint2* __restrict__ sattr1)
{
    __shared__ int lcnt[MAXNB];       // per-bucket counts
    __shared__ int excl[MAXNB];       // block-local exclusive base per bucket
    __shared__ int gb[MAXNB];         // global dest base per bucket for this block
    __shared__ int wsum[16];
    __shared__ unsigned sp_st[HALF];  // staged packed sp
    __shared__ uint2   sat_st[HALF];  // staged packed attr
    __shared__ int     gd_st[HALF];   // staged global dest
    int t = threadIdx.x;
    int lane = t & 63, wv = t >> 6;
    const int* row = M + (long long)blockIdx.x * NB;
    gb[t]   = (t < NB) ? (bb[t] + row[t]) : 0;
    lcnt[t] = 0;
    __syncthreads();
    long long beg = (long long)blockIdx.x * CHUNK;
    long long end = beg + CHUNK; if (end > ne) end = ne;
    int nloc = (int)(end - beg);
    // ---- phase A: read edges once, payload in regs, rank via LDS atomics
    unsigned pk8[8]; uint2 a8[8]; int k8[8], r8[8];
#pragma unroll
    for (int j = 0; j < 8; ++j) {
        long long e = beg + t + (long long)j * 1024;
        if (e < end) {
            int s = ei[e];
            int d = ei[ne + e];
            a8[j] = pack4(attr[e]);
            int k = d >> BSH;
            k8[j] = k;
            pk8[j] = (unsigned)s | ((unsigned)(d & (BSZ - 1)) << 20);
            r8[j] = atomicAdd(&lcnt[k], 1);
        } else k8[j] = -1;
    }
    __syncthreads();
    // ---- phase B: wave-shuffle scan of lcnt -> excl
    int c = lcnt[t];
    int inc = wave_iscan(c, lane);
    if (lane == 63) wsum[wv] = inc;
    __syncthreads();
    if (t < 16) {
        int s2 = wsum[t];
#pragma unroll
        for (int d = 1; d < 16; d <<= 1) {
            int u = __shfl_up(s2, d, 64);
            if (t >= d) s2 += u;
        }
        wsum[t] = s2;
    }
    __syncthreads();
    excl[t] = inc - c + ((wv == 0) ? 0 : wsum[wv - 1]);
    __syncthreads();
    int idx8[8];
#pragma unroll
    for (int j = 0; j < 8; ++j)
        idx8[j] = (k8[j] >= 0) ? (excl[k8[j]] + r8[j]) : -1;
    // ---- phases C/D: two staging passes, coalesced global writes
#pragma unroll
    for (int q = 0; q < 2; ++q) {
        int lo = q * HALF;
#pragma unroll
        for (int j = 0; j < 8; ++j) {
            int idx = idx8[j] - lo;
            if (idx8[j] >= 0 && idx >= 0 && idx < HALF) {
                sp_st[idx]  = pk8[j];
                sat_st[idx] = a8[j];
                gd_st[idx]  = gb[k8[j]] + r8[j];
            }
        }
        __syncthreads();
        for (int p = t; p < HALF; p += 1024) {
            int gp = lo + p;
            if (gp < nloc) {
                int gd = gd_st[p];
                sp1[gd]    = sp_st[p];
                sattr1[gd] = sat_st[p];
            }
        }
        __syncthreads();
    }
}

// ---------------- P3: within-bucket counting sort by local dst -> dst-sorted CSR + off[]
__global__ __launch_bounds__(1024) void k_p3(
    const unsigned* __restrict__ sp1, const uint2* __restrict__ sattr1,
    const int* __restrict__ bb, int NB, long long nn,
    unsigned* __restrict__ sp2, uint2* __restrict__ sattr2, int* __restrict__ off)
{
    __shared__ int cnt[BSZ];
    __shared__ int stage[BSZ];
    __shared__ int wsum0;
    int k = blockIdx.x, t = threadIdx.x;
    int lane = t & 63, wv = t >> 6;
    int beg = bb[k], end = bb[k + 1];
    if (t < BSZ) cnt[t] = 0;
    __syncthreads();
    for (int e = beg + t; e < end; e += 1024)
        atomicAdd(&cnt[sp1[e] >> 20], 1);
    __syncthreads();
    if (t < BSZ) {
        int c = cnt[t];
        int inc = wave_iscan(c, lane);
        stage[t] = inc;
        if (lane == 63 && wv == 0) wsum0 = inc;
    }
    __syncthreads();
    if (t < BSZ) {
        int c = cnt[t];
        int incl = stage[t] + ((wv == 1) ? wsum0 : 0);
        int excl = beg + incl - c;
        long long n = (long long)k * BSZ + t;
        if (n < nn) off[n] = excl;
        cnt[t] = excl;                          // becomes scatter counter
    }
    if (k == NB - 1 && t == 0) off[nn] = end;
    __syncthreads();
    for (int e = beg + t; e < end; e += 1024) {
        unsigned pk = sp1[e];
        int ld = pk >> 20;
        int p = atomicAdd(&cnt[ld], 1);
        sp2[p] = pk & 0xFFFFF;
        sattr2[p] = sattr1[e];
    }
}

// ---------------- Layer 0: 16 lanes/node, dim-per-lane; fp16 x table, packed attr
__global__ __launch_bounds__(256) void k_layer0(
    const __half* __restrict__ xp, long long nn, const int* __restrict__ off,
    const unsigned* __restrict__ sp2, const uint2* __restrict__ sattr2,
    const float* __restrict__ Wec1, const float* __restrict__ bec1,
    const float* __restrict__ Wl, const float* __restrict__ bl,
    __half* __restrict__ hout)
{
    __shared__ float sW1[64], sb1[16], sWl[16 * 17], sbl[16];
    int t = threadIdx.x;
    if (t < 64)  sW1[t] = (t < 48) ? Wec1[t] : 0.f;
    if (t < 16)  sb1[t] = (t < 12) ? bec1[t] : 0.f;
    { int i = t >> 4, j = t & 15;
      sWl[i * 17 + j] = (i < 15 && j < 12) ? Wl[i * 12 + j] : 0.f; }
    if (t < 16)  sbl[t] = (t < 15) ? bl[t] : 0.f;
    __syncthreads();
    int g = t >> 4, l = t & 15;
    long long n = (long long)blockIdx.x * 16 + g;
    if (n >= nn) return;
    int beg = off[n], end = off[n + 1];
    float w0 = sW1[l*4+0], w1 = sW1[l*4+1], w2 = sW1[l*4+2], w3 = sW1[l*4+3];
    float b1 = sb1[l];
    float xn = __half2float(xp[(n << 4) + l]);
    float acc = 0.f;
#pragma unroll 8
    for (int e = beg; e < end; ++e) {
        unsigned s = sp2[e];
        float4 a = unpack4(sattr2[e]);
        float xs = __half2float(xp[((long long)s << 4) + l]);
        float ea = b1 + w0 * a.x + w1 * a.y + w2 * a.z + w3 * a.w;
        acc += fmaxf(xs + ea, 0.f);
    }
    float v = xn + acc;
    float r = sbl[l];
#pragma unroll
    for (int j = 0; j < 12; ++j) {
        float vj = __shfl(v, j, 16);
        r += vj * sWl[l * 17 + j];
    }
    float o = r > 0.f ? r : expm1f(r);
    hout[(n << 4) + l] = __float2half_rn((l < 15) ? o : 0.f);
}

// ---------------- Layers 1/2: folded edge transform, fp16 h, packed attr
template<bool POOL, bool STORE>
__global__ __launch_bounds__(256) void k_layerK(
    const __half* __restrict__ h, long long nn, const int* __restrict__ off,
    const unsigned* __restrict__ sp2, const uint2* __restrict__ sattr2,
    const float* __restrict__ Wec1, const float* __restrict__ bec1,
    const float* __restrict__ Wec2, const float* __restrict__ bec2,
    const float* __restrict__ Wl, const float* __restrict__ bl,
    __half* __restrict__ hout, const int* __restrict__ batch, float* __restrict__ pooled)
{
    __shared__ float sW12[64], sb12[16], sWl[16 * 17], sbl[16];
    int t = threadIdx.x;
    if (t < 64) {                        // fold W12 = Wec2 @ Wec1 (15x4, row 15 zero)
        int i = t >> 2, kk = t & 3;
        float a = 0.f;
        if (i < 15) {
#pragma unroll
            for (int j = 0; j < 12; ++j) a += Wec2[i*12+j] * Wec1[j*4+kk];
        }
        sW12[t] = a;
    }
    if (t < 16) {                        // b12 = Wec2 @ bec1 + bec2
        float a = 0.f;
        if (t < 15) {
            a = bec2[t];
#pragma unroll
            for (int j = 0; j < 12; ++j) a += Wec2[t*12+j] * bec1[j];
        }
        sb12[t] = a;
    }
    { int i = t >> 4, j = t & 15;
      sWl[i * 17 + j] = (i < 15 && j < 15) ? Wl[i * 15 + j] : 0.f; }
    if (t < 16) sbl[t] = (t < 15) ? bl[t] : 0.f;
    __syncthreads();
    int g = t >> 4, l = t & 15;
    long long n = (long long)blockIdx.x * 16 + g;
    if (n >= nn) return;
    int beg = off[n], end = off[n + 1];
    float w0 = sW12[l*4+0], w1 = sW12[l*4+1], w2 = sW12[l*4+2], w3 = sW12[l*4+3];
    float b12 = sb12[l];
    float hn = __half2float(h[(n << 4) + l]);
    float acc = 0.f;
#pragma unroll 8
    for (int e = beg; e < end; ++e) {
        unsigned s = sp2[e];
        float4 a = unpack4(sattr2[e]);
        float hs = __half2float(h[((long long)s << 4) + l]);
        float e2 = b12 + w0 * a.x + w1 * a.y + w2 * a.z + w3 * a.w;
        acc += fmaxf(hs + e2, 0.f);
    }
    float v = hn + acc;
    float r = sbl[l];
#pragma unroll
    for (int j = 0; j < 15; ++j) {
        float vj = __shfl(v, j, 16);
        r += vj * sWl[l * 17 + j];
    }
    float o = r > 0.f ? r : expm1f(r);
    if (STORE) hout[(n << 4) + l] = __float2half_rn((l < 15) ? o : 0.f);
    if (POOL && l < 15) atomicAdd(&pooled[(long long)batch[n] * HS + l], o);
}

// ---------------- Head
__global__ __launch_bounds__(256) void k_head(
    const float* __restrict__ pooled, long long ng,
    const float* __restrict__ Wo1, const float* __restrict__ bo1,
    const float* __restrict__ Wo2, const float* __restrict__ bo2,
    float* __restrict__ out)
{
    long long g = (long long)blockIdx.x * 256 + threadIdx.x;
    if (g >= ng) return;
    float p[15], m[15];
#pragma unroll
    for (int j = 0; j < 15; ++j) p[j] = pooled[g * HS + j];
#pragma unroll
    for (int i = 0; i < 15; ++i) {
        float acc = bo1[i];
#pragma unroll
        for (int j = 0; j < 15; ++j) acc += p[j] * Wo1[i * 15 + j];
        m[i] = acc;
    }
#pragma unroll
    for (int i = 0; i < 2; ++i) {
        float acc = bo2[i];
#pragma unroll
        for (int j = 0; j < 15; ++j) acc += m[j] * Wo2[i * 15 + j];
        out[g * 2 + i] = acc;
    }
}

extern "C" void kernel_launch(void* const* d_in, const int* in_sizes, int n_in,
                              void* d_out, int out_size, void* d_ws, size_t ws_size,
                              hipStream_t stream)
{
    const float* x    = (const float*)d_in[0];
    const int*   ei   = (const int*)d_in[1];
    const float* attr = (const float*)d_in[2];
    const int*   batch= (const int*)d_in[3];
    const float* Wec1 = (const float*)d_in[4];
    const float* bec1 = (const float*)d_in[5];
    const float* Wec2 = (const float*)d_in[6];
    const float* bec2 = (const float*)d_in[7];
    const float* Wl0  = (const float*)d_in[8];
    const float* bl0  = (const float*)d_in[9];
    const float* Wl1  = (const float*)d_in[10];
    const float* bl1  = (const float*)d_in[11];
    const float* Wl2  = (const float*)d_in[12];
    const float* bl2  = (const float*)d_in[13];
    const float* Wo1  = (const float*)d_in[14];
    const float* bo1  = (const float*)d_in[15];
    const float* Wo2  = (const float*)d_in[16];
    const float* bo2  = (const float*)d_in[17];

    const long long nn = in_sizes[0] / D_NODE;   // 100000
    const long long ne = in_sizes[1] / 2;        // 3200000
    const long long ng = out_size / 2;           // 1024

    const int NB   = (int)((nn + BSZ - 1) >> BSH);           // 782
    const int nblk = (int)((ne + CHUNK - 1) / CHUNK);        // 391

    // ---- workspace layout ----
    char* w = (char*)d_ws;
    uint2*    sattr1 = (uint2*)w;                 w += (size_t)ne * sizeof(uint2);
    unsigned* sp1    = (unsigned*)w;              w += (size_t)ne * sizeof(unsigned);
    uint2*    sattr2 = (uint2*)w;                 w += (size_t)ne * sizeof(uint2);
    unsigned* sp2    = (unsigned*)w;              w += (size_t)ne * sizeof(unsigned);
    int*      M      = (int*)w;                   w += (size_t)nblk * NB * sizeof(int);
    int*      tot    = (int*)w;                   w += (size_t)NB * sizeof(int);
    int*      bb     = (int*)w;                   w += ((size_t)NB + 1) * sizeof(int);
    int*      off    = (int*)w;                   w += ((size_t)nn + 1) * sizeof(int);
    w = (char*)(((uintptr_t)w + 15) & ~(uintptr_t)15);
    __half*   xp     = (__half*)w;                w += (size_t)nn * HS * sizeof(__half);
    // overlay: hA/hB/pooled reuse the sattr1 region (dead after k_p3)
    __half*   hA     = (__half*)sattr1;
    __half*   hB     = hA + (size_t)nn * HS;
    float*    pooled = (float*)(hB + (size_t)nn * HS);
    float*    out    = (float*)d_out;

    // ---- x -> fp16 padded table (independent of sort) ----
    k_xcvt<<<(int)((nn * HS + 255) / 256), 256, 0, stream>>>(x, nn, xp);

    // ---- build full dst-sorted CSR (shared by all 3 layers) ----
    k_p1<<<nblk, 1024, 0, stream>>>(ei, ne, NB, M);
    k_colscan<<<NB, 256, 0, stream>>>(M, nblk, NB, tot);
    k_bb<<<1, 1024, 0, stream>>>(tot, NB, bb);
    k_p2<<<nblk, 1024, 0, stream>>>(ei, ne, (const float4*)attr, M, bb, NB, sp1, sattr1);
    k_p3<<<NB, 1024, 0, stream>>>(sp1, sattr1, bb, NB, nn, sp2, sattr2, off);

    // ---- layers (16 lanes per node, dim-per-lane) ----
    const int lblk = (int)((nn + 15) / 16);      // 6250
    k_layer0<<<lblk, 256, 0, stream>>>(xp, nn, off, sp2, sattr2, Wec1, bec1, Wl0, bl0, hA);
    k_layerK<false, true><<<lblk, 256, 0, stream>>>(hA, nn, off, sp2, sattr2,
        Wec1, bec1, Wec2, bec2, Wl1, bl1, hB, nullptr, nullptr);
    hipMemsetAsync(pooled, 0, (size_t)ng * HS * sizeof(float), stream);
    k_layerK<true, false><<<lblk, 256, 0, stream>>>(hB, nn, off, sp2, sattr2,
        Wec1, bec1, Wec2, bec2, Wl2, bl2, nullptr, batch, pooled);

    // ---- head ----
    k_head<<<(int)((ng + 255) / 256), 256, 0, stream>>>(pooled, ng, Wo1, bo1, Wo2, bo2, out);
}